// Round 8
// baseline (130.457 us; speedup 1.0000x reference)
//
#include <hip/hip_runtime.h>
#include <stdint.h>

#define T_ 256
#define B_ 8
#define E_ 512
#define H_ 32
#define HD_ 16
#define EXP_ 512
#define S_ 768          // T_ + EXP_
#define M_ 2048         // T_ * B_
#define SMOOTH_ 20.0f
#define PSTR 36         // P-tile LDS row stride (bf16)
#define VSTR 800        // V^T LDS row stride (bf16)
#define OSTR 20         // O-combine LDS row stride (f32, 16B-aligned rows)

typedef __attribute__((ext_vector_type(8)))  short bf16x8;
typedef __attribute__((ext_vector_type(4)))  float f32x4;
typedef __attribute__((ext_vector_type(16))) float f32x16;

// RNE pack: two fp32 -> one dword of two bf16 (lo=a, hi=b)
__device__ __forceinline__ unsigned int pk2(float a, float b)
{
    unsigned int ua = __float_as_uint(a);
    ua = ua + 0x7FFFu + ((ua >> 16) & 1u);
    unsigned int ub = __float_as_uint(b);
    ub = ub + 0x7FFFu + ((ub >> 16) & 1u);
    return (ua >> 16) | (ub & 0xFFFF0000u);
}
__device__ __forceinline__ ushort bf1(float a)
{
    unsigned int u = __float_as_uint(a);
    u = u + 0x7FFFu + ((u >> 16) & 1u);
    return (ushort)(u >> 16);
}

union U16 { uint4 u; bf16x8 v; };

// ---------------------------------------------------------------------------
// conv: fp32 -> bf16 for X (4 segs) and Wq/Wk/Wv/Wo (1 seg each).
// ---------------------------------------------------------------------------
__global__ __launch_bounds__(256)
void conv_kernel(const float* __restrict__ X,
                 const float* __restrict__ Wq, const float* __restrict__ Wk,
                 const float* __restrict__ Wv, const float* __restrict__ Wo,
                 ushort* __restrict__ Xb, ushort* __restrict__ Wb)
{
    const int seg = blockIdx.x >> 6;
    const int blk = blockIdx.x & 63;
    const float* src;
    ushort* dst;
    if (seg < 4) { src = X + (size_t)seg * 262144; dst = Xb + (size_t)seg * 262144; }
    else {
        const float* ws_[4] = {Wq, Wk, Wv, Wo};
        src = ws_[seg - 4];
        dst = Wb + (size_t)(seg - 4) * 262144;
    }
    const int base = blk * 4096 + threadIdx.x * 16;
    float4 f0 = *(const float4*)&src[base + 0];
    float4 f1 = *(const float4*)&src[base + 4];
    float4 f2 = *(const float4*)&src[base + 8];
    float4 f3 = *(const float4*)&src[base + 12];
    *(uint4*)&dst[base + 0] = make_uint4(pk2(f0.x, f0.y), pk2(f0.z, f0.w),
                                         pk2(f1.x, f1.y), pk2(f1.z, f1.w));
    *(uint4*)&dst[base + 8] = make_uint4(pk2(f2.x, f2.y), pk2(f2.z, f2.w),
                                         pk2(f3.x, f3.y), pk2(f3.z, f3.w));
}

// ---------------------------------------------------------------------------
// bf16 MFMA GEMM body (unchanged from round 7).
// ---------------------------------------------------------------------------
__device__ __forceinline__ void mfma_gemm_body_bf(const ushort* __restrict__ X,
                                                  const ushort* __restrict__ W,
                                                  int m0, int n0,
                                                  f32x4 acc[2][2],
                                                  ushort* As, ushort* Bs)
{
    const int tid  = threadIdx.x;
    const int lrow = tid >> 2;
    const int kq   = tid & 3;
    const int l    = tid & 63;
    const int w    = tid >> 6;
    const int wm   = w & 1;
    const int wn   = w >> 1;
    const int lq   = l >> 4;
    const int ln   = l & 15;

    const ushort* Xr = &X[(size_t)(m0 + lrow) * E_ + kq * 16];
    const ushort* Wr = &W[(size_t)(n0 + lrow) * E_ + kq * 16];
    ushort* Aw = &As[lrow * 72 + kq * 16];
    ushort* Bw = &Bs[lrow * 72 + kq * 16];

    for (int k0 = 0; k0 < E_; k0 += 64) {
        uint4 a0 = *(const uint4*)&Xr[k0 + 0];
        uint4 a1 = *(const uint4*)&Xr[k0 + 8];
        uint4 b0 = *(const uint4*)&Wr[k0 + 0];
        uint4 b1 = *(const uint4*)&Wr[k0 + 8];
        __syncthreads();
        *(uint4*)&Aw[0] = a0;
        *(uint4*)&Aw[8] = a1;
        *(uint4*)&Bw[0] = b0;
        *(uint4*)&Bw[8] = b1;
        __syncthreads();
#pragma unroll
        for (int kb = 0; kb < 2; ++kb) {
            bf16x8 af0 = *(const bf16x8*)&As[(32 * wm + ln) * 72 + 32 * kb + lq * 8];
            bf16x8 af1 = *(const bf16x8*)&As[(32 * wm + 16 + ln) * 72 + 32 * kb + lq * 8];
            bf16x8 bf0 = *(const bf16x8*)&Bs[(32 * wn + ln) * 72 + 32 * kb + lq * 8];
            bf16x8 bf1 = *(const bf16x8*)&Bs[(32 * wn + 16 + ln) * 72 + 32 * kb + lq * 8];
            acc[0][0] = __builtin_amdgcn_mfma_f32_16x16x32_bf16(af0, bf0, acc[0][0], 0, 0, 0);
            acc[0][1] = __builtin_amdgcn_mfma_f32_16x16x32_bf16(af0, bf1, acc[0][1], 0, 0, 0);
            acc[1][0] = __builtin_amdgcn_mfma_f32_16x16x32_bf16(af1, bf0, acc[1][0], 0, 0, 0);
            acc[1][1] = __builtin_amdgcn_mfma_f32_16x16x32_bf16(af1, bf1, acc[1][1], 0, 0, 0);
        }
    }
}

__global__ __launch_bounds__(256)
void qkv_gemm(const ushort* __restrict__ Xb, const ushort* __restrict__ Wb,
              const float* __restrict__ bq, const float* __restrict__ bv,
              ushort* __restrict__ Qb, ushort* __restrict__ Kb,
              ushort* __restrict__ VTb)
{
    __shared__ __align__(16) ushort As[64 * 72];
    __shared__ __align__(16) ushort Bs[64 * 72];
    const int z = blockIdx.z;
    const ushort* W    = Wb + (size_t)z * 262144;
    const float*  bias = (z == 0) ? bq : (z == 2 ? bv : nullptr);

    const int m0 = blockIdx.y * 64;
    const int n0 = blockIdx.x * 64;

    f32x4 acc[2][2];
#pragma unroll
    for (int i = 0; i < 2; ++i)
#pragma unroll
        for (int j = 0; j < 2; ++j)
            acc[i][j] = (f32x4){0.f, 0.f, 0.f, 0.f};

    mfma_gemm_body_bf(Xb, W, m0, n0, acc, As, Bs);

    const int l  = threadIdx.x & 63;
    const int w  = threadIdx.x >> 6;
    const int wm = w & 1;
    const int wn = w >> 1;
    const int lq = l >> 4;
    const int ln = l & 15;

#pragma unroll
    for (int j = 0; j < 2; ++j) {
        const int nb = n0 + 32 * wn + 16 * j;
        const int h  = nb >> 4;
        const int d  = ln;
        const float bv_ = bias ? bias[nb + ln] : 0.f;
#pragma unroll
        for (int i = 0; i < 2; ++i) {
#pragma unroll
            for (int r = 0; r < 4; ++r) {
                const int m = m0 + 32 * wm + 16 * i + lq * 4 + r;
                const int t = m >> 3;
                const int b = m & 7;
                const int bh = b * H_ + h;
                const ushort val = bf1(acc[i][j][r] + bv_);
                if (z == 0)      Qb[((size_t)bh * T_ + t) * HD_ + d] = val;
                else if (z == 1) Kb[((size_t)bh * T_ + t) * HD_ + d] = val;
                else             VTb[((size_t)bh * HD_ + d) * T_ + t] = val;
            }
        }
    }
}

__global__ __launch_bounds__(256)
void out_gemm(const ushort* __restrict__ Ab, const ushort* __restrict__ Wob,
              const float* __restrict__ bo, float* __restrict__ dst)
{
    __shared__ __align__(16) ushort As[64 * 72];
    __shared__ __align__(16) ushort Bs[64 * 72];
    const int m0 = blockIdx.y * 64;
    const int n0 = blockIdx.x * 64;

    f32x4 acc[2][2];
#pragma unroll
    for (int i = 0; i < 2; ++i)
#pragma unroll
        for (int j = 0; j < 2; ++j)
            acc[i][j] = (f32x4){0.f, 0.f, 0.f, 0.f};

    mfma_gemm_body_bf(Ab, Wob, m0, n0, acc, As, Bs);

    const int l  = threadIdx.x & 63;
    const int w  = threadIdx.x >> 6;
    const int wm = w & 1;
    const int wn = w >> 1;
    const int lq = l >> 4;
    const int ln = l & 15;

#pragma unroll
    for (int j = 0; j < 2; ++j) {
        const int nb = n0 + 32 * wn + 16 * j;
        const float bo_ = bo[nb + ln];
#pragma unroll
        for (int i = 0; i < 2; ++i) {
#pragma unroll
            for (int r = 0; r < 4; ++r) {
                const int m = m0 + 32 * wm + 16 * i + lq * 4 + r;
                dst[(size_t)m * E_ + nb + ln] = acc[i][j][r] + bo_;
            }
        }
    }
}

// ---------------------------------------------------------------------------
// Attention v6: 512 threads / 8 waves per block = (b,h) x t-half.
// Wave w: t-tile wt = w&3 (32 rows), s-half sh = w>>2 (12 of 24 s-tiles).
// Staging (spread over 512 threads): Ks[768][16] bf16 incl. oc-expansion,
// Vt[16][VSTR] bf16 incl. expansion, msf[768]. Barrier-free s-loop:
// S^T = mfma_32x32x16(K,Q); fixed-ref softmax; P=e*law bf16 -> per-wave
// LDS tile; O^T += mfma_16x16x32(V^T,P). Cross-s-half combine of (O,Z)
// through a buffer aliased onto Ks after one barrier; epilogue by sh==0.
// LDS 70 KB -> 2 blocks/CU -> 16 waves/CU = 4 waves/SIMD.
// ---------------------------------------------------------------------------
__global__ __launch_bounds__(512)
void attn_kernel(const ushort* __restrict__ Qb, const ushort* __restrict__ Kb,
                 const ushort* __restrict__ VTb, const float* __restrict__ LAW,
                 const int* __restrict__ kpm, const int* __restrict__ em,
                 const int* __restrict__ oc, ushort* __restrict__ Ab)
{
    __shared__ __align__(16) ushort Ks[S_ * HD_];       // 24576 B
    __shared__ __align__(16) ushort Vt[HD_ * VSTR];     // 25600 B
    __shared__ __align__(16) float  msf[S_];            // 3072 B
    __shared__ __align__(16) ushort Pb[8][32 * PSTR];   // 18432 B   total ~70 KB

    float* Obuf = (float*)Ks;                 // alias: 128 rows x OSTR f32
    float* Zb   = (float*)Ks + 128 * OSTR;    // 128 f32 (alias, still in Ks)

    const int tid    = threadIdx.x;
    const int blk    = blockIdx.x;
    const int bh     = blk >> 1;
    const int thalf  = blk & 1;
    const int b      = bh >> 5;
    const int h      = bh & 31;

    // ---- stage K rows 0..255 (512 x uint4) ----
    ((uint4*)Ks)[tid] = ((const uint4*)&Kb[(size_t)bh * T_ * HD_])[tid];
    // ---- stage V^T cols 0..255 (512 x uint4) ----
    {
        const int row = tid >> 5, ch = tid & 31;
        *(uint4*)&Vt[row * VSTR + ch * 8] =
            *(const uint4*)&VTb[((size_t)bh * HD_ + row) * T_ + ch * 8];
    }
    // ---- expansion 256..767 via oc (one j per thread) ----
    {
        const int j   = tid;
        const int src = oc[b * EXP_ + j];
        const uint4* kr = (const uint4*)&Kb[((size_t)bh * T_ + src) * HD_];
        *(uint4*)&Ks[(T_ + j) * HD_ + 0] = kr[0];
        *(uint4*)&Ks[(T_ + j) * HD_ + 8] = kr[1];
#pragma unroll
        for (int d = 0; d < 16; ++d)
            Vt[d * VSTR + T_ + j] = VTb[((size_t)bh * HD_ + d) * T_ + src];
    }
    // ---- masks ----
    {
        const int s = tid;
        const int m = (s < T_) ? kpm[b * T_ + s] : em[b * EXP_ + (s - T_)];
        msf[s] = m ? 0.f : 1.f;
        if (tid < 256) {
            const int s2 = 512 + tid;
            msf[s2] = em[b * EXP_ + (s2 - T_)] ? 0.f : 1.f;
        }
    }

    const int w      = tid >> 6;
    const int l      = tid & 63;
    const int tloc   = l & 31;
    const int khalf  = l >> 5;
    const int wt     = w & 3;
    const int sh     = w >> 2;
    const int tglob  = thalf * 128 + wt * 32 + tloc;
    bf16x8 qf = *(const bf16x8*)&Qb[((size_t)bh * T_ + tglob) * HD_ + khalf * 8];

    __syncthreads();

    const f32x16 zero16 = {0.f,0.f,0.f,0.f,0.f,0.f,0.f,0.f,
                           0.f,0.f,0.f,0.f,0.f,0.f,0.f,0.f};
    f32x4 o0 = {0.f, 0.f, 0.f, 0.f};
    f32x4 o1 = {0.f, 0.f, 0.f, 0.f};
    float Z = 0.f;

    const float* lawp = &LAW[((size_t)b * T_ + tglob) * S_];
    ushort* prow = &Pb[w][tloc * PSTR];
    const int tl = l & 15;
    const int kg = l >> 4;

    for (int i = sh * 12; i < sh * 12 + 12; ++i) {
        bf16x8 kf = *(const bf16x8*)&Ks[(i * 32 + tloc) * HD_ + khalf * 8];
        f32x16 sc = __builtin_amdgcn_mfma_f32_32x32x16_bf16(kf, qf, zero16, 0, 0, 0);

#pragma unroll
        for (int qd = 0; qd < 4; ++qd) {
            const int sb = i * 32 + qd * 8 + khalf * 4;
            float4 mf = *(const float4*)&msf[sb];
            float4 lw = *(const float4*)&lawp[sb];
            float e0, e1, e2, e3;
            {
                float x = (sc[qd*4+0] + SMOOTH_) * lw.x - SMOOTH_;
                e0 = mf.x * __expf(x - 50.f);
                x = (sc[qd*4+1] + SMOOTH_) * lw.y - SMOOTH_;
                e1 = mf.y * __expf(x - 50.f);
                x = (sc[qd*4+2] + SMOOTH_) * lw.z - SMOOTH_;
                e2 = mf.z * __expf(x - 50.f);
                x = (sc[qd*4+3] + SMOOTH_) * lw.w - SMOOTH_;
                e3 = mf.w * __expf(x - 50.f);
            }
            Z += (e0 + e1) + (e2 + e3);
            *(uint2*)&prow[qd * 8 + khalf * 4] =
                make_uint2(pk2(e0 * lw.x, e1 * lw.y), pk2(e2 * lw.z, e3 * lw.w));
        }

        bf16x8 vf = *(const bf16x8*)&Vt[tl * VSTR + i * 32 + kg * 8];
        {
            const ushort* pr0 = &Pb[w][(0 * 16 + tl) * PSTR + kg * 8];
            U16 u;
            uint2 a0 = *(const uint2*)pr0;
            uint2 a1 = *(const uint2*)(pr0 + 4);
            u.u = make_uint4(a0.x, a0.y, a1.x, a1.y);
            o0 = __builtin_amdgcn_mfma_f32_16x16x32_bf16(vf, u.v, o0, 0, 0, 0);
            const ushort* pr1 = &Pb[w][(1 * 16 + tl) * PSTR + kg * 8];
            uint2 b0 = *(const uint2*)pr1;
            uint2 b1 = *(const uint2*)(pr1 + 4);
            u.u = make_uint4(b0.x, b0.y, b1.x, b1.y);
            o1 = __builtin_amdgcn_mfma_f32_16x16x32_bf16(vf, u.v, o1, 0, 0, 0);
        }
    }

    // khalf merge (lanes l, l^32 share tloc)
    Z += __shfl_xor(Z, 32);

    __syncthreads();              // all loops done; Ks may be aliased now

    if (sh == 1) {
#pragma unroll
        for (int th = 0; th < 2; ++th) {
            const f32x4 o = th ? o1 : o0;
            *(float4*)&Obuf[((wt * 2 + th) * 16 + tl) * OSTR + kg * 4] =
                make_float4(o[0], o[1], o[2], o[3]);
        }
        if (l < 32) Zb[wt * 32 + tloc] = Z;
    }
    __syncthreads();

    if (sh == 0) {
        const float Ztot = Z + Zb[wt * 32 + tloc];   // Z for t = tloc
#pragma unroll
        for (int th = 0; th < 2; ++th) {
            const float Zt  = __shfl(Ztot, th * 16 + tl);
            const float inv = (Zt > 0.f) ? 1.f / Zt : 0.f;
            float4 po = *(const float4*)&Obuf[((wt * 2 + th) * 16 + tl) * OSTR + kg * 4];
            const f32x4 o = th ? o1 : o0;
            const int t = thalf * 128 + wt * 32 + th * 16 + tl;
            float ov[4] = {o[0] + po.x, o[1] + po.y, o[2] + po.z, o[3] + po.w};
#pragma unroll
            for (int r = 0; r < 4; ++r) {
                const int d = kg * 4 + r;
                Ab[((size_t)t * B_ + b) * E_ + h * HD_ + d] = bf1(ov[r] * inv);
            }
        }
    }
}

// ---------------------------------------------------------------------------
extern "C" void kernel_launch(void* const* d_in, const int* in_sizes, int n_in,
                              void* d_out, int out_size, void* d_ws, size_t ws_size,
                              hipStream_t stream)
{
    const float* query = (const float*)d_in[0];
    const int*   oc    = (const int*)d_in[1];
    const int*   em    = (const int*)d_in[2];
    const int*   kpm   = (const int*)d_in[3];
    const float* law   = (const float*)d_in[4];
    const float* Wq    = (const float*)d_in[5];
    const float* bq    = (const float*)d_in[6];
    const float* Wk    = (const float*)d_in[7];
    const float* Wv    = (const float*)d_in[8];
    const float* bv    = (const float*)d_in[9];
    const float* Wo    = (const float*)d_in[10];
    const float* bo    = (const float*)d_in[11];
    float* out = (float*)d_out;

    ushort* Xb  = (ushort*)d_ws;                 // [m][e]      1,048,576
    ushort* Wb  = Xb  + (size_t)1048576;         // 4x[n][k]    1,048,576
    ushort* Qb  = Wb  + (size_t)1048576;         // [bh][t][16] 1,048,576
    ushort* Kb  = Qb  + (size_t)1048576;         // [bh][t][16] 1,048,576
    ushort* VTb = Kb  + (size_t)1048576;         // [bh][d][t]  1,048,576
    ushort* Ab  = VTb + (size_t)1048576;         // [m][e]      1,048,576

    conv_kernel<<<512, 256, 0, stream>>>(query, Wq, Wk, Wv, Wo, Xb, Wb);

    dim3 gq(E_ / 64, M_ / 64, 3);
    qkv_gemm<<<gq, 256, 0, stream>>>(Xb, Wb, bq, bv, Qb, Kb, VTb);

    attn_kernel<<<B_ * H_ * 2, 512, 0, stream>>>(Qb, Kb, VTb, law, kpm, em, oc, Ab);

    dim3 go(E_ / 64, M_ / 64, 1);
    out_gemm<<<go, 256, 0, stream>>>(Ab, Wb + (size_t)3 * 262144, bo, out);
}

// Round 9
// 129.200 us; speedup vs baseline: 1.0097x; 1.0097x over previous
//
#include <hip/hip_runtime.h>
#include <stdint.h>

#define T_ 256
#define B_ 8
#define E_ 512
#define H_ 32
#define HD_ 16
#define EXP_ 512
#define S_ 768          // T_ + EXP_
#define M_ 2048         // T_ * B_
#define SMOOTH_ 20.0f
#define PSTR 36         // P-tile LDS row stride (bf16)
#define VSTR 800        // V^T LDS row stride (bf16)
#define OSTR 20         // O-combine LDS row stride (f32)

typedef __attribute__((ext_vector_type(8)))  short bf16x8;
typedef __attribute__((ext_vector_type(4)))  float f32x4;
typedef __attribute__((ext_vector_type(16))) float f32x16;

__device__ __forceinline__ unsigned int pk2(float a, float b)
{
    unsigned int ua = __float_as_uint(a);
    ua = ua + 0x7FFFu + ((ua >> 16) & 1u);
    unsigned int ub = __float_as_uint(b);
    ub = ub + 0x7FFFu + ((ub >> 16) & 1u);
    return (ua >> 16) | (ub & 0xFFFF0000u);
}
__device__ __forceinline__ ushort bf1(float a)
{
    unsigned int u = __float_as_uint(a);
    u = u + 0x7FFFu + ((u >> 16) & 1u);
    return (ushort)(u >> 16);
}

union U16 { uint4 u; bf16x8 v; };

// ---------------------------------------------------------------------------
// conv: fp32 -> bf16 for X (4 segs) and Wq/Wk/Wv/Wo.
// ---------------------------------------------------------------------------
__global__ __launch_bounds__(256)
void conv_kernel(const float* __restrict__ X,
                 const float* __restrict__ Wq, const float* __restrict__ Wk,
                 const float* __restrict__ Wv, const float* __restrict__ Wo,
                 ushort* __restrict__ Xb, ushort* __restrict__ Wb)
{
    const int seg = blockIdx.x >> 6;
    const int blk = blockIdx.x & 63;
    const float* src;
    ushort* dst;
    if (seg < 4) { src = X + (size_t)seg * 262144; dst = Xb + (size_t)seg * 262144; }
    else {
        const float* ws_[4] = {Wq, Wk, Wv, Wo};
        src = ws_[seg - 4];
        dst = Wb + (size_t)(seg - 4) * 262144;
    }
    const int base = blk * 4096 + threadIdx.x * 16;
    float4 f0 = *(const float4*)&src[base + 0];
    float4 f1 = *(const float4*)&src[base + 4];
    float4 f2 = *(const float4*)&src[base + 8];
    float4 f3 = *(const float4*)&src[base + 12];
    *(uint4*)&dst[base + 0] = make_uint4(pk2(f0.x, f0.y), pk2(f0.z, f0.w),
                                         pk2(f1.x, f1.y), pk2(f1.z, f1.w));
    *(uint4*)&dst[base + 8] = make_uint4(pk2(f2.x, f2.y), pk2(f2.z, f2.w),
                                         pk2(f3.x, f3.y), pk2(f3.z, f3.w));
}

// ---------------------------------------------------------------------------
// bf16 MFMA GEMM body with prefetch: caller supplies per-thread source
// pointers (row, kq-chunk for k0=0) + per-64k step. Next tile's global
// loads are issued right after the barrier, in flight during ds_read+MFMA.
// ---------------------------------------------------------------------------
__device__ __forceinline__ void mfma_gemm_body_bf(const ushort* __restrict__ Xr,
                                                  int xstep,
                                                  const ushort* __restrict__ Wr,
                                                  int wstep,
                                                  f32x4 acc[2][2],
                                                  ushort* As, ushort* Bs)
{
    const int tid  = threadIdx.x;
    const int lrow = tid >> 2;
    const int kq   = tid & 3;
    const int l    = tid & 63;
    const int w    = tid >> 6;
    const int wm   = w & 1;
    const int wn   = w >> 1;
    const int lq   = l >> 4;
    const int ln   = l & 15;

    ushort* Aw = &As[lrow * 72 + kq * 16];
    ushort* Bw = &Bs[lrow * 72 + kq * 16];

    uint4 a0 = *(const uint4*)&Xr[0];
    uint4 a1 = *(const uint4*)&Xr[8];
    uint4 b0 = *(const uint4*)&Wr[0];
    uint4 b1 = *(const uint4*)&Wr[8];

    for (int it = 0; it < E_ / 64; ++it) {
        __syncthreads();
        *(uint4*)&Aw[0] = a0;
        *(uint4*)&Aw[8] = a1;
        *(uint4*)&Bw[0] = b0;
        *(uint4*)&Bw[8] = b1;
        __syncthreads();
        if (it < E_ / 64 - 1) {
            Xr += xstep; Wr += wstep;
            a0 = *(const uint4*)&Xr[0];
            a1 = *(const uint4*)&Xr[8];
            b0 = *(const uint4*)&Wr[0];
            b1 = *(const uint4*)&Wr[8];
        }
#pragma unroll
        for (int kb = 0; kb < 2; ++kb) {
            bf16x8 af0 = *(const bf16x8*)&As[(32 * wm + ln) * 72 + 32 * kb + lq * 8];
            bf16x8 af1 = *(const bf16x8*)&As[(32 * wm + 16 + ln) * 72 + 32 * kb + lq * 8];
            bf16x8 bf0 = *(const bf16x8*)&Bs[(32 * wn + ln) * 72 + 32 * kb + lq * 8];
            bf16x8 bf1 = *(const bf16x8*)&Bs[(32 * wn + 16 + ln) * 72 + 32 * kb + lq * 8];
            acc[0][0] = __builtin_amdgcn_mfma_f32_16x16x32_bf16(af0, bf0, acc[0][0], 0, 0, 0);
            acc[0][1] = __builtin_amdgcn_mfma_f32_16x16x32_bf16(af0, bf1, acc[0][1], 0, 0, 0);
            acc[1][0] = __builtin_amdgcn_mfma_f32_16x16x32_bf16(af1, bf0, acc[1][0], 0, 0, 0);
            acc[1][1] = __builtin_amdgcn_mfma_f32_16x16x32_bf16(af1, bf1, acc[1][1], 0, 0, 0);
        }
    }
}

// ---------------------------------------------------------------------------
// qkv GEMM: all of z=0/1/2 write row-major [bh][t][16] bf16 (Qb/Kb/Vb).
// Epilogue bounced through LDS -> 2 x uint4 coalesced stores per thread.
// ---------------------------------------------------------------------------
__global__ __launch_bounds__(256)
void qkv_gemm(const ushort* __restrict__ Xb, const ushort* __restrict__ Wb,
              const float* __restrict__ bq, const float* __restrict__ bv,
              ushort* __restrict__ Qb, ushort* __restrict__ Kb,
              ushort* __restrict__ Vb)
{
    __shared__ __align__(16) ushort AsBs[2 * 64 * 72];
    ushort* As = AsBs;
    ushort* Bs = AsBs + 64 * 72;

    const int z = blockIdx.z;
    const ushort* W    = Wb + (size_t)z * 262144;
    const float*  bias = (z == 0) ? bq : (z == 2 ? bv : nullptr);
    ushort* dst        = (z == 0) ? Qb : (z == 1 ? Kb : Vb);

    const int m0 = blockIdx.y * 64;
    const int n0 = blockIdx.x * 64;

    f32x4 acc[2][2];
#pragma unroll
    for (int i = 0; i < 2; ++i)
#pragma unroll
        for (int j = 0; j < 2; ++j)
            acc[i][j] = (f32x4){0.f, 0.f, 0.f, 0.f};

    const int tid  = threadIdx.x;
    const int lrow = tid >> 2;
    const int kq   = tid & 3;
    mfma_gemm_body_bf(&Xb[(size_t)(m0 + lrow) * E_ + kq * 16], 64,
                      &W[(size_t)(n0 + lrow) * E_ + kq * 16], 64,
                      acc, As, Bs);

    const int l  = tid & 63;
    const int w  = tid >> 6;
    const int wm = w & 1;
    const int wn = w >> 1;
    const int lq = l >> 4;
    const int ln = l & 15;

    const float b0_ = bias ? bias[n0 + 32 * wn + ln]      : 0.f;
    const float b1_ = bias ? bias[n0 + 32 * wn + 16 + ln] : 0.f;

    __syncthreads();
    ushort* Ls = As;   // 64 x 72
#pragma unroll
    for (int j = 0; j < 2; ++j) {
        const float bb = j ? b1_ : b0_;
#pragma unroll
        for (int i = 0; i < 2; ++i)
#pragma unroll
            for (int r = 0; r < 4; ++r)
                Ls[(32 * wm + 16 * i + lq * 4 + r) * 72 + 32 * wn + 16 * j + ln] =
                    bf1(acc[i][j][r] + bb);
    }
    __syncthreads();

    {
        const int lm = tid & 63;
        const int hh = tid >> 6;
        uint4 f0 = *(const uint4*)&Ls[lm * 72 + hh * 16];
        uint4 f1 = *(const uint4*)&Ls[lm * 72 + hh * 16 + 8];
        const int m = m0 + lm;
        const int t = m >> 3;
        const int b = m & 7;
        const int h = (n0 >> 4) + hh;
        ushort* dp = &dst[(((size_t)(b * H_ + h)) * T_ + t) * HD_];
        *(uint4*)&dp[0] = f0;
        *(uint4*)&dp[8] = f1;
    }
}

// ---------------------------------------------------------------------------
// out GEMM: A = Ab bf16 [b][h][t][16]; epilogue via LDS -> 4 float4/thread.
// ---------------------------------------------------------------------------
__global__ __launch_bounds__(256)
void out_gemm(const ushort* __restrict__ Ab, const ushort* __restrict__ Wob,
              const float* __restrict__ bo, float* __restrict__ dst)
{
    __shared__ __align__(16) ushort AsBs[2 * 64 * 72];
    ushort* As = AsBs;
    ushort* Bs = AsBs + 64 * 72;

    const int m0 = blockIdx.y * 64;
    const int n0 = blockIdx.x * 64;

    f32x4 acc[2][2];
#pragma unroll
    for (int i = 0; i < 2; ++i)
#pragma unroll
        for (int j = 0; j < 2; ++j)
            acc[i][j] = (f32x4){0.f, 0.f, 0.f, 0.f};

    const int tid  = threadIdx.x;
    const int lrow = tid >> 2;
    const int kq   = tid & 3;
    const int m    = m0 + lrow;
    const int t    = m >> 3;
    const int b    = m & 7;
    // A row for k-chunk: h = (k0>>4)+kq, addr = ((b*H + h)*T + t)*HD
    mfma_gemm_body_bf(&Ab[(((size_t)(b * H_ + kq)) * T_ + t) * HD_], 4 * T_ * HD_,
                      &Wob[(size_t)(n0 + lrow) * E_ + kq * 16], 64,
                      acc, As, Bs);

    const int l  = tid & 63;
    const int w  = tid >> 6;
    const int wm = w & 1;
    const int wn = w >> 1;
    const int lq = l >> 4;
    const int ln = l & 15;

    const float bo0 = bo[n0 + 32 * wn + ln];
    const float bo1 = bo[n0 + 32 * wn + 16 + ln];

    __syncthreads();
    float* Lf = (float*)AsBs;   // 64 x 68 f32 = 17408 B
#pragma unroll
    for (int j = 0; j < 2; ++j) {
        const float bb = j ? bo1 : bo0;
#pragma unroll
        for (int i = 0; i < 2; ++i)
#pragma unroll
            for (int r = 0; r < 4; ++r)
                Lf[(32 * wm + 16 * i + lq * 4 + r) * 68 + 32 * wn + 16 * j + ln] =
                    acc[i][j][r] + bb;
    }
    __syncthreads();

    {
        const int lm = tid & 63;
        const int hh = tid >> 6;
        float* dp = &dst[(size_t)(m0 + lm) * E_ + n0 + hh * 16];
#pragma unroll
        for (int c = 0; c < 4; ++c) {
            float4 v = *(const float4*)&Lf[lm * 68 + hh * 16 + c * 4];
            *(float4*)&dp[c * 4] = v;
        }
    }
}

// ---------------------------------------------------------------------------
// scatter 8 bf16 (one uint4) into V^T columns (stride VSTR per d)
// ---------------------------------------------------------------------------
__device__ __forceinline__ void scat8(ushort* d, uint4 u)
{
    d[0 * VSTR] = (ushort)(u.x);  d[1 * VSTR] = (ushort)(u.x >> 16);
    d[2 * VSTR] = (ushort)(u.y);  d[3 * VSTR] = (ushort)(u.y >> 16);
    d[4 * VSTR] = (ushort)(u.z);  d[5 * VSTR] = (ushort)(u.z >> 16);
    d[6 * VSTR] = (ushort)(u.w);  d[7 * VSTR] = (ushort)(u.w >> 16);
}

// ---------------------------------------------------------------------------
// Attention v7: as v6 (512 thr / 8 waves, t-half x s-half) but:
//  - V^T staged from row-major Vb (in-LDS transpose; expansion = row gathers)
//  - output Ab in [b][h][t][16] layout, written via LDS bounce as one
//    contiguous 4 KB coalesced store region per block.
// ---------------------------------------------------------------------------
__global__ __launch_bounds__(512)
void attn_kernel(const ushort* __restrict__ Qb, const ushort* __restrict__ Kb,
                 const ushort* __restrict__ Vb, const float* __restrict__ LAW,
                 const int* __restrict__ kpm, const int* __restrict__ em,
                 const int* __restrict__ oc, ushort* __restrict__ Ab)
{
    __shared__ __align__(16) ushort Ks[S_ * HD_];       // 24576 B
    __shared__ __align__(16) ushort Vt[HD_ * VSTR];     // 25600 B
    __shared__ __align__(16) float  msf[S_];            // 3072 B
    __shared__ __align__(16) ushort Pb[8][32 * PSTR];   // 18432 B

    float* Obuf = (float*)Ks;                 // alias after loop
    float* Zb   = (float*)Ks + 128 * OSTR;
    ushort* Ob  = (ushort*)Pb;                // alias after loop: 128x16 bf16

    const int tid    = threadIdx.x;
    const int blk    = blockIdx.x;
    const int bh     = blk >> 1;
    const int thalf  = blk & 1;
    const int b      = bh >> 5;
    const int h      = bh & 31;

    // ---- stage K rows 0..255 ----
    ((uint4*)Ks)[tid] = ((const uint4*)&Kb[(size_t)bh * T_ * HD_])[tid];
    // ---- stage V^T cols 0..255 from row-major Vb ----
    {
        const int t    = tid >> 1;
        const int half = tid & 1;
        uint4 v = *(const uint4*)&Vb[((size_t)bh * T_ + t) * HD_ + half * 8];
        scat8(&Vt[half * 8 * VSTR + t], v);
    }
    // ---- expansion 256..767 via oc (row gathers) ----
    {
        const int j   = tid;
        const int src = oc[b * EXP_ + j];
        const uint4* kr = (const uint4*)&Kb[((size_t)bh * T_ + src) * HD_];
        *(uint4*)&Ks[(T_ + j) * HD_ + 0] = kr[0];
        *(uint4*)&Ks[(T_ + j) * HD_ + 8] = kr[1];
        const uint4* vr = (const uint4*)&Vb[((size_t)bh * T_ + src) * HD_];
        scat8(&Vt[T_ + j], vr[0]);
        scat8(&Vt[8 * VSTR + T_ + j], vr[1]);
    }
    // ---- masks ----
    {
        const int s = tid;
        const int m = (s < T_) ? kpm[b * T_ + s] : em[b * EXP_ + (s - T_)];
        msf[s] = m ? 0.f : 1.f;
        if (tid < 256) {
            const int s2 = 512 + tid;
            msf[s2] = em[b * EXP_ + (s2 - T_)] ? 0.f : 1.f;
        }
    }

    const int w      = tid >> 6;
    const int l      = tid & 63;
    const int tloc   = l & 31;
    const int khalf  = l >> 5;
    const int wt     = w & 3;
    const int sh     = w >> 2;
    const int tglob  = thalf * 128 + wt * 32 + tloc;
    bf16x8 qf = *(const bf16x8*)&Qb[((size_t)bh * T_ + tglob) * HD_ + khalf * 8];

    __syncthreads();

    const f32x16 zero16 = {0.f,0.f,0.f,0.f,0.f,0.f,0.f,0.f,
                           0.f,0.f,0.f,0.f,0.f,0.f,0.f,0.f};
    f32x4 o0 = {0.f, 0.f, 0.f, 0.f};
    f32x4 o1 = {0.f, 0.f, 0.f, 0.f};
    float Z = 0.f;

    const float* lawp = &LAW[((size_t)b * T_ + tglob) * S_];
    ushort* prow = &Pb[w][tloc * PSTR];
    const int tl = l & 15;
    const int kg = l >> 4;

    for (int i = sh * 12; i < sh * 12 + 12; ++i) {
        bf16x8 kf = *(const bf16x8*)&Ks[(i * 32 + tloc) * HD_ + khalf * 8];
        f32x16 sc = __builtin_amdgcn_mfma_f32_32x32x16_bf16(kf, qf, zero16, 0, 0, 0);

#pragma unroll
        for (int qd = 0; qd < 4; ++qd) {
            const int sb = i * 32 + qd * 8 + khalf * 4;
            float4 mf = *(const float4*)&msf[sb];
            float4 lw = *(const float4*)&lawp[sb];
            float e0, e1, e2, e3;
            {
                float x = (sc[qd*4+0] + SMOOTH_) * lw.x - SMOOTH_;
                e0 = mf.x * __expf(x - 50.f);
                x = (sc[qd*4+1] + SMOOTH_) * lw.y - SMOOTH_;
                e1 = mf.y * __expf(x - 50.f);
                x = (sc[qd*4+2] + SMOOTH_) * lw.z - SMOOTH_;
                e2 = mf.z * __expf(x - 50.f);
                x = (sc[qd*4+3] + SMOOTH_) * lw.w - SMOOTH_;
                e3 = mf.w * __expf(x - 50.f);
            }
            Z += (e0 + e1) + (e2 + e3);
            *(uint2*)&prow[qd * 8 + khalf * 4] =
                make_uint2(pk2(e0 * lw.x, e1 * lw.y), pk2(e2 * lw.z, e3 * lw.w));
        }

        bf16x8 vf = *(const bf16x8*)&Vt[tl * VSTR + i * 32 + kg * 8];
        {
            const ushort* pr0 = &Pb[w][(0 * 16 + tl) * PSTR + kg * 8];
            U16 u;
            uint2 a0 = *(const uint2*)pr0;
            uint2 a1 = *(const uint2*)(pr0 + 4);
            u.u = make_uint4(a0.x, a0.y, a1.x, a1.y);
            o0 = __builtin_amdgcn_mfma_f32_16x16x32_bf16(vf, u.v, o0, 0, 0, 0);
            const ushort* pr1 = &Pb[w][(1 * 16 + tl) * PSTR + kg * 8];
            uint2 b0 = *(const uint2*)pr1;
            uint2 b1 = *(const uint2*)(pr1 + 4);
            u.u = make_uint4(b0.x, b0.y, b1.x, b1.y);
            o1 = __builtin_amdgcn_mfma_f32_16x16x32_bf16(vf, u.v, o1, 0, 0, 0);
        }
    }

    Z += __shfl_xor(Z, 32);      // merge khalf s-subsets (same tloc)

    __syncthreads();             // loops done; Ks/Pb may be aliased

    if (sh == 1) {
#pragma unroll
        for (int th = 0; th < 2; ++th) {
            const f32x4 o = th ? o1 : o0;
            *(float4*)&Obuf[((wt * 2 + th) * 16 + tl) * OSTR + kg * 4] =
                make_float4(o[0], o[1], o[2], o[3]);
        }
        if (l < 32) Zb[wt * 32 + tloc] = Z;
    }
    __syncthreads();

    if (sh == 0) {
        const float Ztot = Z + Zb[wt * 32 + tloc];
#pragma unroll
        for (int th = 0; th < 2; ++th) {
            const float Zt  = __shfl(Ztot, th * 16 + tl);
            const float inv = (Zt > 0.f) ? 1.f / Zt : 0.f;
            float4 po = *(const float4*)&Obuf[((wt * 2 + th) * 16 + tl) * OSTR + kg * 4];
            const f32x4 o = th ? o1 : o0;
            const int trow = wt * 32 + th * 16 + tl;   // 0..127
            float ov[4] = {(o[0] + po.x) * inv, (o[1] + po.y) * inv,
                           (o[2] + po.z) * inv, (o[3] + po.w) * inv};
            *(uint*)&Ob[trow * 16 + kg * 4]     = pk2(ov[0], ov[1]);
            *(uint*)&Ob[trow * 16 + kg * 4 + 2] = pk2(ov[2], ov[3]);
        }
    }
    __syncthreads();

    if (tid < 256) {
        ushort* dp = &Ab[(((size_t)(b * H_ + h)) * T_ + thalf * 128) * HD_];
        *(uint4*)&dp[tid * 8] = *(const uint4*)&Ob[tid * 8];
    }
}

// ---------------------------------------------------------------------------
extern "C" void kernel_launch(void* const* d_in, const int* in_sizes, int n_in,
                              void* d_out, int out_size, void* d_ws, size_t ws_size,
                              hipStream_t stream)
{
    const float* query = (const float*)d_in[0];
    const int*   oc    = (const int*)d_in[1];
    const int*   em    = (const int*)d_in[2];
    const int*   kpm   = (const int*)d_in[3];
    const float* law   = (const float*)d_in[4];
    const float* Wq    = (const float*)d_in[5];
    const float* bq    = (const float*)d_in[6];
    const float* Wk    = (const float*)d_in[7];
    const float* Wv    = (const float*)d_in[8];
    const float* bv    = (const float*)d_in[9];
    const float* Wo    = (const float*)d_in[10];
    const float* bo    = (const float*)d_in[11];
    float* out = (float*)d_out;

    ushort* Xb  = (ushort*)d_ws;                 // [m][e]
    ushort* Wb  = Xb  + (size_t)1048576;         // 4x[n][k]
    ushort* Qb  = Wb  + (size_t)1048576;         // [bh][t][16]
    ushort* Kb  = Qb  + (size_t)1048576;         // [bh][t][16]
    ushort* Vb  = Kb  + (size_t)1048576;         // [bh][t][16]
    ushort* Ab  = Vb  + (size_t)1048576;         // [b][h][t][16]

    conv_kernel<<<512, 256, 0, stream>>>(query, Wq, Wk, Wv, Wo, Xb, Wb);

    dim3 gq(E_ / 64, M_ / 64, 3);
    qkv_gemm<<<gq, 256, 0, stream>>>(Xb, Wb, bq, bv, Qb, Kb, Vb);

    attn_kernel<<<B_ * H_ * 2, 512, 0, stream>>>(Qb, Kb, Vb, law, kpm, em, oc, Ab);

    dim3 go(E_ / 64, M_ / 64, 1);
    out_gemm<<<go, 256, 0, stream>>>(Ab, Wb + (size_t)3 * 262144, bo, out);
}

// Round 10
// 126.509 us; speedup vs baseline: 1.0312x; 1.0213x over previous
//
#include <hip/hip_runtime.h>
#include <stdint.h>

#define T_ 256
#define B_ 8
#define E_ 512
#define H_ 32
#define HD_ 16
#define EXP_ 512
#define S_ 768          // T_ + EXP_
#define M_ 2048         // T_ * B_
#define SMOOTH_ 20.0f
#define PSTR 40         // P-tile LDS row stride (bf16): rows t,t+4 -> disjoint bank halves
#define VSTR 800        // V^T LDS row stride (bf16)
#define OSTR 20         // O-combine LDS row stride (f32)

typedef __attribute__((ext_vector_type(8)))  short bf16x8;
typedef __attribute__((ext_vector_type(4)))  float f32x4;
typedef __attribute__((ext_vector_type(16))) float f32x16;

__device__ __forceinline__ unsigned int pk2(float a, float b)
{
    unsigned int ua = __float_as_uint(a);
    ua = ua + 0x7FFFu + ((ua >> 16) & 1u);
    unsigned int ub = __float_as_uint(b);
    ub = ub + 0x7FFFu + ((ub >> 16) & 1u);
    return (ua >> 16) | (ub & 0xFFFF0000u);
}
__device__ __forceinline__ ushort bf1(float a)
{
    unsigned int u = __float_as_uint(a);
    u = u + 0x7FFFu + ((u >> 16) & 1u);
    return (ushort)(u >> 16);
}

union U16 { uint4 u; bf16x8 v; };

// ---------------------------------------------------------------------------
// conv: fp32 -> bf16 for X (4 segs) and Wq/Wk/Wv/Wo.  (unchanged)
// ---------------------------------------------------------------------------
__global__ __launch_bounds__(256)
void conv_kernel(const float* __restrict__ X,
                 const float* __restrict__ Wq, const float* __restrict__ Wk,
                 const float* __restrict__ Wv, const float* __restrict__ Wo,
                 ushort* __restrict__ Xb, ushort* __restrict__ Wb)
{
    const int seg = blockIdx.x >> 6;
    const int blk = blockIdx.x & 63;
    const float* src;
    ushort* dst;
    if (seg < 4) { src = X + (size_t)seg * 262144; dst = Xb + (size_t)seg * 262144; }
    else {
        const float* ws_[4] = {Wq, Wk, Wv, Wo};
        src = ws_[seg - 4];
        dst = Wb + (size_t)(seg - 4) * 262144;
    }
    const int base = blk * 4096 + threadIdx.x * 16;
    float4 f0 = *(const float4*)&src[base + 0];
    float4 f1 = *(const float4*)&src[base + 4];
    float4 f2 = *(const float4*)&src[base + 8];
    float4 f3 = *(const float4*)&src[base + 12];
    *(uint4*)&dst[base + 0] = make_uint4(pk2(f0.x, f0.y), pk2(f0.z, f0.w),
                                         pk2(f1.x, f1.y), pk2(f1.z, f1.w));
    *(uint4*)&dst[base + 8] = make_uint4(pk2(f2.x, f2.y), pk2(f2.z, f2.w),
                                         pk2(f3.x, f3.y), pk2(f3.z, f3.w));
}

// ---------------------------------------------------------------------------
// bf16 MFMA GEMM body with prefetch (unchanged from round 9).
// ---------------------------------------------------------------------------
__device__ __forceinline__ void mfma_gemm_body_bf(const ushort* __restrict__ Xr,
                                                  int xstep,
                                                  const ushort* __restrict__ Wr,
                                                  int wstep,
                                                  f32x4 acc[2][2],
                                                  ushort* As, ushort* Bs)
{
    const int tid  = threadIdx.x;
    const int lrow = tid >> 2;
    const int kq   = tid & 3;
    const int l    = tid & 63;
    const int w    = tid >> 6;
    const int wm   = w & 1;
    const int wn   = w >> 1;
    const int lq   = l >> 4;
    const int ln   = l & 15;

    ushort* Aw = &As[lrow * 72 + kq * 16];
    ushort* Bw = &Bs[lrow * 72 + kq * 16];

    uint4 a0 = *(const uint4*)&Xr[0];
    uint4 a1 = *(const uint4*)&Xr[8];
    uint4 b0 = *(const uint4*)&Wr[0];
    uint4 b1 = *(const uint4*)&Wr[8];

    for (int it = 0; it < E_ / 64; ++it) {
        __syncthreads();
        *(uint4*)&Aw[0] = a0;
        *(uint4*)&Aw[8] = a1;
        *(uint4*)&Bw[0] = b0;
        *(uint4*)&Bw[8] = b1;
        __syncthreads();
        if (it < E_ / 64 - 1) {
            Xr += xstep; Wr += wstep;
            a0 = *(const uint4*)&Xr[0];
            a1 = *(const uint4*)&Xr[8];
            b0 = *(const uint4*)&Wr[0];
            b1 = *(const uint4*)&Wr[8];
        }
#pragma unroll
        for (int kb = 0; kb < 2; ++kb) {
            bf16x8 af0 = *(const bf16x8*)&As[(32 * wm + ln) * 72 + 32 * kb + lq * 8];
            bf16x8 af1 = *(const bf16x8*)&As[(32 * wm + 16 + ln) * 72 + 32 * kb + lq * 8];
            bf16x8 bf0 = *(const bf16x8*)&Bs[(32 * wn + ln) * 72 + 32 * kb + lq * 8];
            bf16x8 bf1 = *(const bf16x8*)&Bs[(32 * wn + 16 + ln) * 72 + 32 * kb + lq * 8];
            acc[0][0] = __builtin_amdgcn_mfma_f32_16x16x32_bf16(af0, bf0, acc[0][0], 0, 0, 0);
            acc[0][1] = __builtin_amdgcn_mfma_f32_16x16x32_bf16(af0, bf1, acc[0][1], 0, 0, 0);
            acc[1][0] = __builtin_amdgcn_mfma_f32_16x16x32_bf16(af1, bf0, acc[1][0], 0, 0, 0);
            acc[1][1] = __builtin_amdgcn_mfma_f32_16x16x32_bf16(af1, bf1, acc[1][1], 0, 0, 0);
        }
    }
}

// ---------------------------------------------------------------------------
// qkv GEMM (unchanged from round 9).
// ---------------------------------------------------------------------------
__global__ __launch_bounds__(256)
void qkv_gemm(const ushort* __restrict__ Xb, const ushort* __restrict__ Wb,
              const float* __restrict__ bq, const float* __restrict__ bv,
              ushort* __restrict__ Qb, ushort* __restrict__ Kb,
              ushort* __restrict__ Vb)
{
    __shared__ __align__(16) ushort AsBs[2 * 64 * 72];
    ushort* As = AsBs;
    ushort* Bs = AsBs + 64 * 72;

    const int z = blockIdx.z;
    const ushort* W    = Wb + (size_t)z * 262144;
    const float*  bias = (z == 0) ? bq : (z == 2 ? bv : nullptr);
    ushort* dst        = (z == 0) ? Qb : (z == 1 ? Kb : Vb);

    const int m0 = blockIdx.y * 64;
    const int n0 = blockIdx.x * 64;

    f32x4 acc[2][2];
#pragma unroll
    for (int i = 0; i < 2; ++i)
#pragma unroll
        for (int j = 0; j < 2; ++j)
            acc[i][j] = (f32x4){0.f, 0.f, 0.f, 0.f};

    const int tid  = threadIdx.x;
    const int lrow = tid >> 2;
    const int kq   = tid & 3;
    mfma_gemm_body_bf(&Xb[(size_t)(m0 + lrow) * E_ + kq * 16], 64,
                      &W[(size_t)(n0 + lrow) * E_ + kq * 16], 64,
                      acc, As, Bs);

    const int l  = tid & 63;
    const int w  = tid >> 6;
    const int wm = w & 1;
    const int wn = w >> 1;
    const int lq = l >> 4;
    const int ln = l & 15;

    const float b0_ = bias ? bias[n0 + 32 * wn + ln]      : 0.f;
    const float b1_ = bias ? bias[n0 + 32 * wn + 16 + ln] : 0.f;

    __syncthreads();
    ushort* Ls = As;
#pragma unroll
    for (int j = 0; j < 2; ++j) {
        const float bb = j ? b1_ : b0_;
#pragma unroll
        for (int i = 0; i < 2; ++i)
#pragma unroll
            for (int r = 0; r < 4; ++r)
                Ls[(32 * wm + 16 * i + lq * 4 + r) * 72 + 32 * wn + 16 * j + ln] =
                    bf1(acc[i][j][r] + bb);
    }
    __syncthreads();

    {
        const int lm = tid & 63;
        const int hh = tid >> 6;
        uint4 f0 = *(const uint4*)&Ls[lm * 72 + hh * 16];
        uint4 f1 = *(const uint4*)&Ls[lm * 72 + hh * 16 + 8];
        const int m = m0 + lm;
        const int t = m >> 3;
        const int b = m & 7;
        const int h = (n0 >> 4) + hh;
        ushort* dp = &dst[(((size_t)(b * H_ + h)) * T_ + t) * HD_];
        *(uint4*)&dp[0] = f0;
        *(uint4*)&dp[8] = f1;
    }
}

// ---------------------------------------------------------------------------
// out GEMM (unchanged from round 9).
// ---------------------------------------------------------------------------
__global__ __launch_bounds__(256)
void out_gemm(const ushort* __restrict__ Ab, const ushort* __restrict__ Wob,
              const float* __restrict__ bo, float* __restrict__ dst)
{
    __shared__ __align__(16) ushort AsBs[2 * 64 * 72];
    ushort* As = AsBs;
    ushort* Bs = AsBs + 64 * 72;

    const int m0 = blockIdx.y * 64;
    const int n0 = blockIdx.x * 64;

    f32x4 acc[2][2];
#pragma unroll
    for (int i = 0; i < 2; ++i)
#pragma unroll
        for (int j = 0; j < 2; ++j)
            acc[i][j] = (f32x4){0.f, 0.f, 0.f, 0.f};

    const int tid  = threadIdx.x;
    const int lrow = tid >> 2;
    const int kq   = tid & 3;
    const int m    = m0 + lrow;
    const int t    = m >> 3;
    const int b    = m & 7;
    mfma_gemm_body_bf(&Ab[(((size_t)(b * H_ + kq)) * T_ + t) * HD_], 4 * T_ * HD_,
                      &Wob[(size_t)(n0 + lrow) * E_ + kq * 16], 64,
                      acc, As, Bs);

    const int l  = tid & 63;
    const int w  = tid >> 6;
    const int wm = w & 1;
    const int wn = w >> 1;
    const int lq = l >> 4;
    const int ln = l & 15;

    const float bo0 = bo[n0 + 32 * wn + ln];
    const float bo1 = bo[n0 + 32 * wn + 16 + ln];

    __syncthreads();
    float* Lf = (float*)AsBs;
#pragma unroll
    for (int j = 0; j < 2; ++j) {
        const float bb = j ? bo1 : bo0;
#pragma unroll
        for (int i = 0; i < 2; ++i)
#pragma unroll
            for (int r = 0; r < 4; ++r)
                Lf[(32 * wm + 16 * i + lq * 4 + r) * 68 + 32 * wn + 16 * j + ln] =
                    acc[i][j][r] + bb;
    }
    __syncthreads();

    {
        const int lm = tid & 63;
        const int hh = tid >> 6;
        float* dp = &dst[(size_t)(m0 + lm) * E_ + n0 + hh * 16];
#pragma unroll
        for (int c = 0; c < 4; ++c) {
            float4 v = *(const float4*)&Lf[lm * 68 + hh * 16 + c * 4];
            *(float4*)&dp[c * 4] = v;
        }
    }
}

__device__ __forceinline__ void scat8(ushort* d, uint4 u)
{
    d[0 * VSTR] = (ushort)(u.x);  d[1 * VSTR] = (ushort)(u.x >> 16);
    d[2 * VSTR] = (ushort)(u.y);  d[3 * VSTR] = (ushort)(u.y >> 16);
    d[4 * VSTR] = (ushort)(u.z);  d[5 * VSTR] = (ushort)(u.z >> 16);
    d[6 * VSTR] = (ushort)(u.w);  d[7 * VSTR] = (ushort)(u.w >> 16);
}

// ---------------------------------------------------------------------------
// Attention v8: s-on-lanes score layout for coalesced law reads.
// S-MFMA operand order swapped vs v7: sc = mfma_32x32x16(Qfrag_A, Kfrag_B)
//   -> C/D col = lane&31 = s_loc, row = (r&3)+8*(r>>2)+4*(lane>>5) = t_loc.
// law: 16 coalesced dword loads/iter (lane = s).  msf: 1 LDS dword/iter.
// Z: zacc[16] per-t register accumulators, 32-lane shuffle tree at end.
// P: 16 ds_write_b16 scatters into per-wave [t][s] tile (PSTR=40: the two
// khalf row groups map to disjoint bank halves).  PV side unchanged.
// ---------------------------------------------------------------------------
__global__ __launch_bounds__(512)
void attn_kernel(const ushort* __restrict__ Qb, const ushort* __restrict__ Kb,
                 const ushort* __restrict__ Vb, const float* __restrict__ LAW,
                 const int* __restrict__ kpm, const int* __restrict__ em,
                 const int* __restrict__ oc, ushort* __restrict__ Ab)
{
    __shared__ __align__(16) ushort Ks[S_ * HD_];       // 24576 B
    __shared__ __align__(16) ushort Vt[HD_ * VSTR];     // 25600 B
    __shared__ __align__(16) float  msf[S_];            // 3072 B
    __shared__ __align__(16) ushort Pb[8][32 * PSTR];   // 20480 B
    __shared__ __align__(16) float  Zpart[2][128];      // 1024 B   total ~73 KB

    float*  Obuf = (float*)Ks;        // alias after loop: 128 x OSTR f32
    ushort* Ob   = (ushort*)Vt;       // alias after loop: 128 x 16 bf16

    const int tid    = threadIdx.x;
    const int blk    = blockIdx.x;
    const int bh     = blk >> 1;
    const int thalf  = blk & 1;
    const int b      = bh >> 5;
    const int h      = bh & 31;

    // ---- stage K rows 0..255 ----
    ((uint4*)Ks)[tid] = ((const uint4*)&Kb[(size_t)bh * T_ * HD_])[tid];
    // ---- stage V^T cols 0..255 from row-major Vb ----
    {
        const int t    = tid >> 1;
        const int half = tid & 1;
        uint4 v = *(const uint4*)&Vb[((size_t)bh * T_ + t) * HD_ + half * 8];
        scat8(&Vt[half * 8 * VSTR + t], v);
    }
    // ---- expansion 256..767 via oc (row gathers) ----
    {
        const int j   = tid;
        const int src = oc[b * EXP_ + j];
        const uint4* kr = (const uint4*)&Kb[((size_t)bh * T_ + src) * HD_];
        *(uint4*)&Ks[(T_ + j) * HD_ + 0] = kr[0];
        *(uint4*)&Ks[(T_ + j) * HD_ + 8] = kr[1];
        const uint4* vr = (const uint4*)&Vb[((size_t)bh * T_ + src) * HD_];
        scat8(&Vt[T_ + j], vr[0]);
        scat8(&Vt[8 * VSTR + T_ + j], vr[1]);
    }
    // ---- masks ----
    {
        const int s = tid;
        const int m = (s < T_) ? kpm[b * T_ + s] : em[b * EXP_ + (s - T_)];
        msf[s] = m ? 0.f : 1.f;
        if (tid < 256) {
            const int s2 = 512 + tid;
            msf[s2] = em[b * EXP_ + (s2 - T_)] ? 0.f : 1.f;
        }
    }

    const int w      = tid >> 6;
    const int l      = tid & 63;
    const int slane  = l & 31;          // s position on lanes
    const int khalf  = l >> 5;
    const int wt     = w & 3;
    const int sh     = w >> 2;
    const int tbase  = thalf * 128 + wt * 32;
    // Q A-frag: m = lane&31 (t), k-chunk = khalf — same load as v7
    bf16x8 qf = *(const bf16x8*)&Qb[((size_t)bh * T_ + tbase + slane) * HD_ + khalf * 8];

    __syncthreads();

    const f32x16 zero16 = {0.f,0.f,0.f,0.f,0.f,0.f,0.f,0.f,
                           0.f,0.f,0.f,0.f,0.f,0.f,0.f,0.f};
    f32x4 o0 = {0.f, 0.f, 0.f, 0.f};
    f32x4 o1 = {0.f, 0.f, 0.f, 0.f};
    float zacc[16];
#pragma unroll
    for (int r = 0; r < 16; ++r) zacc[r] = 0.f;

    // law base for this lane: row (tbase + khalf*4 + trow), col slane
    const float* lawb = &LAW[((size_t)b * T_ + tbase + khalf * 4) * S_ + slane];
    ushort* pw = &Pb[w][slane];
    const int tl = l & 15;
    const int kg = l >> 4;

    for (int i = sh * 12; i < sh * 12 + 12; ++i) {
        // K B-frag: n = lane&31 (s), k-chunk = khalf — same memory as v7
        bf16x8 kf = *(const bf16x8*)&Ks[(i * 32 + slane) * HD_ + khalf * 8];

        // coalesced law loads: 16 dwords, rows trow(r), col i*32+slane
        float lw[16];
        const float* lp = lawb + i * 32;
#pragma unroll
        for (int r = 0; r < 16; ++r)
            lw[r] = lp[(size_t)((r & 3) + 8 * (r >> 2)) * S_];

        f32x16 sc = __builtin_amdgcn_mfma_f32_32x32x16_bf16(qf, kf, zero16, 0, 0, 0);
        const float mval = msf[i * 32 + slane];

#pragma unroll
        for (int r = 0; r < 16; ++r) {
            const float x = (sc[r] + SMOOTH_) * lw[r] - SMOOTH_;
            const float e = mval * __expf(x - 50.f);
            zacc[r] += e;
            pw[((r & 3) + 8 * (r >> 2) + 4 * khalf) * PSTR] = bf1(e * lw[r]);
        }

        bf16x8 vf = *(const bf16x8*)&Vt[tl * VSTR + i * 32 + kg * 8];
        {
            const ushort* pr0 = &Pb[w][(0 * 16 + tl) * PSTR + kg * 8];
            U16 u;
            uint2 a0 = *(const uint2*)pr0;
            uint2 a1 = *(const uint2*)(pr0 + 4);
            u.u = make_uint4(a0.x, a0.y, a1.x, a1.y);
            o0 = __builtin_amdgcn_mfma_f32_16x16x32_bf16(vf, u.v, o0, 0, 0, 0);
            const ushort* pr1 = &Pb[w][(1 * 16 + tl) * PSTR + kg * 8];
            uint2 b0 = *(const uint2*)pr1;
            uint2 b1 = *(const uint2*)(pr1 + 4);
            u.u = make_uint4(b0.x, b0.y, b1.x, b1.y);
            o1 = __builtin_amdgcn_mfma_f32_16x16x32_bf16(vf, u.v, o1, 0, 0, 0);
        }
    }

    // reduce zacc across the 32-lane s-groups (khalf groups stay separate)
#pragma unroll
    for (int m = 1; m < 32; m <<= 1) {
#pragma unroll
        for (int r = 0; r < 16; ++r)
            zacc[r] += __shfl_xor(zacc[r], m);
    }

    __syncthreads();              // loops done; Ks/Vt may be aliased

    if (l == 0 || l == 32) {
#pragma unroll
        for (int r = 0; r < 16; ++r)
            Zpart[sh][wt * 32 + (r & 3) + 8 * (r >> 2) + 4 * khalf] = zacc[r];
    }
    if (sh == 1) {
#pragma unroll
        for (int th = 0; th < 2; ++th) {
            const f32x4 o = th ? o1 : o0;
            *(float4*)&Obuf[((wt * 2 + th) * 16 + tl) * OSTR + kg * 4] =
                make_float4(o[0], o[1], o[2], o[3]);
        }
    }
    __syncthreads();

    if (sh == 0) {
#pragma unroll
        for (int th = 0; th < 2; ++th) {
            const int trow = wt * 32 + th * 16 + tl;    // 0..127
            const float Zt  = Zpart[0][trow] + Zpart[1][trow];
            const float inv = (Zt > 0.f) ? 1.f / Zt : 0.f;
            float4 po = *(const float4*)&Obuf[((wt * 2 + th) * 16 + tl) * OSTR + kg * 4];
            const f32x4 o = th ? o1 : o0;
            float ov[4] = {(o[0] + po.x) * inv, (o[1] + po.y) * inv,
                           (o[2] + po.z) * inv, (o[3] + po.w) * inv};
            *(uint*)&Ob[trow * 16 + kg * 4]     = pk2(ov[0], ov[1]);
            *(uint*)&Ob[trow * 16 + kg * 4 + 2] = pk2(ov[2], ov[3]);
        }
    }
    __syncthreads();

    if (tid < 256) {
        ushort* dp = &Ab[(((size_t)(b * H_ + h)) * T_ + thalf * 128) * HD_];
        *(uint4*)&dp[tid * 8] = *(const uint4*)&Ob[tid * 8];
    }
}

// ---------------------------------------------------------------------------
extern "C" void kernel_launch(void* const* d_in, const int* in_sizes, int n_in,
                              void* d_out, int out_size, void* d_ws, size_t ws_size,
                              hipStream_t stream)
{
    const float* query = (const float*)d_in[0];
    const int*   oc    = (const int*)d_in[1];
    const int*   em    = (const int*)d_in[2];
    const int*   kpm   = (const int*)d_in[3];
    const float* law   = (const float*)d_in[4];
    const float* Wq    = (const float*)d_in[5];
    const float* bq    = (const float*)d_in[6];
    const float* Wk    = (const float*)d_in[7];
    const float* Wv    = (const float*)d_in[8];
    const float* bv    = (const float*)d_in[9];
    const float* Wo    = (const float*)d_in[10];
    const float* bo    = (const float*)d_in[11];
    float* out = (float*)d_out;

    ushort* Xb  = (ushort*)d_ws;                 // [m][e]
    ushort* Wb  = Xb  + (size_t)1048576;         // 4x[n][k]
    ushort* Qb  = Wb  + (size_t)1048576;         // [bh][t][16]
    ushort* Kb  = Qb  + (size_t)1048576;         // [bh][t][16]
    ushort* Vb  = Kb  + (size_t)1048576;         // [bh][t][16]
    ushort* Ab  = Vb  + (size_t)1048576;         // [b][h][t][16]

    conv_kernel<<<512, 256, 0, stream>>>(query, Wq, Wk, Wv, Wo, Xb, Wb);

    dim3 gq(E_ / 64, M_ / 64, 3);
    qkv_gemm<<<gq, 256, 0, stream>>>(Xb, Wb, bq, bv, Qb, Kb, Vb);

    attn_kernel<<<B_ * H_ * 2, 512, 0, stream>>>(Qb, Kb, Vb, law, kpm, em, oc, Ab);

    dim3 go(E_ / 64, M_ / 64, 1);
    out_gemm<<<go, 256, 0, stream>>>(Ab, Wb + (size_t)3 * 262144, bo, out);
}